// Round 4
// baseline (1485.053 us; speedup 1.0000x reference)
//
#include <hip/hip_runtime.h>

// LSTM B=256, T=2048, H=128, gates 4H=512, deferred fc projection.
// Kernel 1: one batch row per WG, 1024 threads = 256 gate-pairs x 4 K-quarters.
//   Thread (gp, kq): gate rows row0 = (gp>>7)*128 + (gp&127)  (i or f)
//                    row1 = row0 + 256                        (z or o)
//   holds 2x16 packed half2 of W_hh over h[kq*32 .. kq*32+32).
//   Reusing each h-load for 2 gate rows HALVES the per-CU h-broadcast
//   ds_read count (the round-3 limiter: waves x h_bytes/16 = 128 b128/step).
//   Phase A: 32 dot2 -> quad shfl_xor combine (DPP) -> activation ->
//   gq[unit] = {i,f,z,o} float4. Phase B (128 threads): one b128 read,
//   cell update, h -> LDS fp16 + fire-and-forget store to d_ws.
//   amdgpu_waves_per_eu(4,4) pins the VGPR budget to 128 so the allocator
//   has no incentive to park weights in AGPRs (rounds 2/3 failure mode).

typedef _Float16 half2v __attribute__((ext_vector_type(2)));

constexpr int NB = 256;
constexpr int NT = 2048;
constexpr int NH = 128;

__device__ __forceinline__ float fexp2(float x) {
    float r;
    asm("v_exp_f32 %0, %1" : "=v"(r) : "v"(x));
    return r;
}
__device__ __forceinline__ float frcp(float x) {
    float r;
    asm("v_rcp_f32 %0, %1" : "=v"(r) : "v"(x));
    return r;
}
__device__ __forceinline__ float fsig(float x) {   // 1/(1+2^(-x*log2e))
    return frcp(1.f + fexp2(x * -1.44269504f));
}
__device__ __forceinline__ float ftanh(float x) {  // 2/(1+2^(-2x*log2e)) - 1
    return fmaf(2.f, frcp(1.f + fexp2(x * -2.88539008f)), -1.f);
}

__device__ __forceinline__ float dot2(unsigned int w, unsigned int h, float acc) {
    half2v a = __builtin_bit_cast(half2v, w);
    half2v b = __builtin_bit_cast(half2v, h);
#if __has_builtin(__builtin_amdgcn_fdot2)
    return __builtin_amdgcn_fdot2(a, b, acc, false);
#else
    float r;
    asm("v_dot2_f32_f16 %0, %1, %2, %3" : "=v"(r) : "v"(a), "v"(b), "v"(acc));
    return r;
#endif
}

__device__ __forceinline__ unsigned packh2(float lo, float hi) {
    half2v p;
    p.x = (_Float16)lo;
    p.y = (_Float16)hi;
    return __builtin_bit_cast(unsigned, p);
}

// barrier with LDS visibility but NO vmcnt drain (keeps fire-and-forget
// global h stores off the 2048-iteration critical path)
__device__ __forceinline__ void barrier_lds() {
    asm volatile("s_waitcnt lgkmcnt(0)" ::: "memory");
    __builtin_amdgcn_s_barrier();
    asm volatile("" ::: "memory");
}

template <bool DEFER_FC>
__global__ __launch_bounds__(1024) __attribute__((amdgpu_waves_per_eu(4, 4)))
void lstm_k1(const float* __restrict__ x, const float* __restrict__ W_ih,
             const float* __restrict__ W_hh, const float* __restrict__ b_ih,
             const float* __restrict__ b_hh, const float* __restrict__ fc_w,
             const float* __restrict__ fc_b, float* __restrict__ out,
             _Float16* __restrict__ hws) {
    __shared__ __align__(16) float    x_lds[NT];
    __shared__ __align__(16) _Float16 h_lds[NH];
    __shared__ __align__(16) float4   gq[NH];   // per unit: {i, f, z, o}
    __shared__ float red[2];                    // fallback fc partials

    const int b    = blockIdx.x;
    const int t    = threadIdx.x;        // 0..1023
    const int kq   = t & 3;              // K-quarter 0..3 (within lane quad)
    const int gp   = t >> 2;             // gate pair 0..255
    const int unit = gp & (NH - 1);      // hidden unit 0..127
    const int ph   = gp >> 7;            // 0: rows i/z, 1: rows f/o
    const int row0 = ph * NH + unit;     // i or f row
    const int row1 = row0 + 2 * NH;      // z or o row

    // preload x row (1024 x float2)
    ((float2*)x_lds)[t] = ((const float2*)(x + (size_t)b * NT))[t];
    if (t < NH) h_lds[t] = (_Float16)0.f;

    // weights: rows row0,row1 over h[kq*32 .. kq*32+32) -> 2x16 half2
    unsigned w0[16], w1[16];
    {
        const float2* p0 = (const float2*)(W_hh + (size_t)row0 * NH + kq * 32);
        const float2* p1 = (const float2*)(W_hh + (size_t)row1 * NH + kq * 32);
#pragma unroll
        for (int k = 0; k < 16; ++k) {
            float2 f0 = p0[k], f1 = p1[k];
            w0[k] = packh2(f0.x, f0.y);
            w1[k] = packh2(f1.x, f1.y);
        }
    }
#pragma unroll
    for (int k = 0; k < 16; ++k) {
        asm volatile("" : "+v"(w0[k]));
        asm volatile("" : "+v"(w1[k]));
    }

    // bias + x-weight: counted once per gate (kq==0 lane of each quad)
    float wih0 = 0.f, wih1 = 0.f, bias0 = 0.f, bias1 = 0.f;
    if (kq == 0) {
        wih0  = W_ih[row0];
        wih1  = W_ih[row1];
        bias0 = b_ih[row0] + b_hh[row0];
        bias1 = b_ih[row1] + b_hh[row1];
    }

    float c = 0.f;                        // cell state (threads t<NH)
    float fcw = 0.f, fcb = 0.f;
    if (!DEFER_FC && t < NH) {
        fcw = fc_w[t];
        fcb = fc_b[0];
    }

    float*    outp = out + (size_t)b * NT;
    _Float16* hrow = DEFER_FC ? (hws + (size_t)b * NT * NH) : (_Float16*)nullptr;

    __syncthreads();

    for (int step = 0; step < NT; ++step) {
        // ---------- phase A: partial dots + quad combine + activation ----------
        float a00 = 0.f, a01 = 0.f, a10 = 0.f, a11 = 0.f;
        const uint4* h4 = (const uint4*)h_lds;
#pragma unroll
        for (int j = 0; j < 4; ++j) {
            uint4 hv = h4[(kq << 2) + j];
            a00 = dot2(w0[4 * j + 0], hv.x, a00);
            a01 = dot2(w0[4 * j + 1], hv.y, a01);
            a00 = dot2(w0[4 * j + 2], hv.z, a00);
            a01 = dot2(w0[4 * j + 3], hv.w, a01);
            a10 = dot2(w1[4 * j + 0], hv.x, a10);
            a11 = dot2(w1[4 * j + 1], hv.y, a11);
            a10 = dot2(w1[4 * j + 2], hv.z, a10);
            a11 = dot2(w1[4 * j + 3], hv.w, a11);
        }
        float xv = x_lds[step];
        float s0 = (a00 + a01) + fmaf(xv, wih0, bias0);
        float s1 = (a10 + a11) + fmaf(xv, wih1, bias1);
        // combine the 4 K-quarters within the lane quad (DPP quad_perm)
        s0 += __shfl_xor(s0, 1);
        s0 += __shfl_xor(s0, 2);
        s1 += __shfl_xor(s1, 1);
        s1 += __shfl_xor(s1, 2);
        if (kq == 0) {
            float act0 = fsig(s0);                       // i or f
            float act1 = ph ? fsig(s1) : ftanh(s1);      // o or z
            float* q = (float*)&gq[unit];
            q[ph]     = act0;   // .x = i  /  .y = f
            q[2 + ph] = act1;   // .z = z  /  .w = o
        }
        barrier_lds();

        // ---------- phase B: cell update (128 threads) ----------
        if (t < NH) {
            float4 gv = gq[t];
            c = fmaf(gv.y, c, gv.x * gv.z);
            float h = gv.w * ftanh(c);
            h_lds[t] = (_Float16)h;
            if (DEFER_FC) {
                hrow[(size_t)step * NH + t] = (_Float16)h;  // fire-and-forget
            } else {
                float p = h * fcw;
#pragma unroll
                for (int m = 32; m >= 1; m >>= 1) p += __shfl_xor(p, m, 64);
                if ((t & 63) == 0) red[t >> 6] = p;
            }
        }
        if (!DEFER_FC) {
            __syncthreads();
            if (t == 0) outp[step] = ftanh(red[0] + red[1] + fcb);
        }
        barrier_lds();
    }

    // ---------- final hT, cT ([1,B,H] each, after out) ----------
    if (t < NH) {
        float* hT = out + (size_t)NB * NT;
        float* cT = hT + (size_t)NB * NH;
        hT[b * NH + t] = (float)h_lds[t];
        cT[b * NH + t] = c;
    }
}

// Kernel 2: out[b,t] = tanh(dot(h[b,t,:], fc_w) + fc_b). Memory-bound.
__global__ __launch_bounds__(256) void fc_k2(const _Float16* __restrict__ hws,
                                             const float* __restrict__ fc_w,
                                             const float* __restrict__ fc_b,
                                             float* __restrict__ out) {
    __shared__ unsigned wlds[64];
    const int t = threadIdx.x;
    if (t < 64) {
        float2 f = ((const float2*)fc_w)[t];
        wlds[t] = packh2(f.x, f.y);
    }
    __syncthreads();

    const size_t idx = (size_t)blockIdx.x * 256 + t;
    const uint4* hp = (const uint4*)(hws + idx * NH);
    const uint4* wp = (const uint4*)wlds;
    float acc = 0.f;
#pragma unroll
    for (int j = 0; j < 16; ++j) {
        uint4 hv = hp[j];
        uint4 wv = wp[j];
        acc = dot2(hv.x, wv.x, acc);
        acc = dot2(hv.y, wv.y, acc);
        acc = dot2(hv.z, wv.z, acc);
        acc = dot2(hv.w, wv.w, acc);
    }
    out[idx] = ftanh(acc + fc_b[0]);
}

extern "C" void kernel_launch(void* const* d_in, const int* in_sizes, int n_in,
                              void* d_out, int out_size, void* d_ws, size_t ws_size,
                              hipStream_t stream) {
    const float* x    = (const float*)d_in[0];
    const float* W_ih = (const float*)d_in[1];
    const float* W_hh = (const float*)d_in[2];
    const float* b_ih = (const float*)d_in[3];
    const float* b_hh = (const float*)d_in[4];
    const float* fc_w = (const float*)d_in[5];
    const float* fc_b = (const float*)d_in[6];
    float* out = (float*)d_out;

    const size_t need = (size_t)NB * NT * NH * sizeof(_Float16);  // 128 MB
    if (ws_size >= need) {
        _Float16* hws = (_Float16*)d_ws;
        lstm_k1<true><<<dim3(NB), dim3(1024), 0, stream>>>(
            x, W_ih, W_hh, b_ih, b_hh, fc_w, fc_b, out, hws);
        fc_k2<<<dim3(NB * NT / 256), dim3(256), 0, stream>>>(hws, fc_w, fc_b, out);
    } else {
        lstm_k1<false><<<dim3(NB), dim3(1024), 0, stream>>>(
            x, W_ih, W_hh, b_ih, b_hh, fc_w, fc_b, out, nullptr);
    }
}

// Round 5
// 1319.354 us; speedup vs baseline: 1.1256x; 1.1256x over previous
//
#include <hip/hip_runtime.h>

// LSTM B=256, T=2048, H=128. One batch row per WG, 512 threads = 128 units
// x 4 K-quarters. Thread (unit,kq) holds the kq*32..kq*32+32 slice of ALL
// FOUR gate rows (i,f,z,o) of its unit: 64 packed half2, asm-pinned.
// Per step (ONE barrier, no phase B, no gate LDS round-trip):
//   4x ds_read_b128 (h slice) -> 64 dot2 -> 8 shfl_xor quad butterfly
//   (all 4 lanes get all 4 full gate sums) -> bias/x post-combine ->
//   activations + cell update REDUNDANTLY on all 4 quad lanes (no
//   divergence) -> kq==0 writes h to double-buffered h_lds (no WAR race)
//   + fire-and-forget global h store -> lgkmcnt-only barrier.
// waves_per_eu(2,2): max occupancy pinned at 2 waves/EU so the register
// allocator has zero incentive to park pinned weights in AGPRs (the
// round-2/3 failure mode). fc projection deferred to memory-bound kernel 2.

typedef _Float16 half2v __attribute__((ext_vector_type(2)));

constexpr int NB = 256;
constexpr int NT = 2048;
constexpr int NH = 128;

__device__ __forceinline__ float fexp2(float x) {
    float r;
    asm("v_exp_f32 %0, %1" : "=v"(r) : "v"(x));
    return r;
}
__device__ __forceinline__ float frcp(float x) {
    float r;
    asm("v_rcp_f32 %0, %1" : "=v"(r) : "v"(x));
    return r;
}
__device__ __forceinline__ float fsig(float x) {   // 1/(1+2^(-x*log2e))
    return frcp(1.f + fexp2(x * -1.44269504f));
}
__device__ __forceinline__ float ftanh(float x) {  // 2/(1+2^(-2x*log2e)) - 1
    return fmaf(2.f, frcp(1.f + fexp2(x * -2.88539008f)), -1.f);
}

__device__ __forceinline__ float dot2(unsigned int w, unsigned int h, float acc) {
    half2v a = __builtin_bit_cast(half2v, w);
    half2v b = __builtin_bit_cast(half2v, h);
#if __has_builtin(__builtin_amdgcn_fdot2)
    return __builtin_amdgcn_fdot2(a, b, acc, false);
#else
    float r;
    asm("v_dot2_f32_f16 %0, %1, %2, %3" : "=v"(r) : "v"(a), "v"(b), "v"(acc));
    return r;
#endif
}

__device__ __forceinline__ unsigned packh2(float lo, float hi) {
    half2v p;
    p.x = (_Float16)lo;
    p.y = (_Float16)hi;
    return __builtin_bit_cast(unsigned, p);
}

// barrier with LDS visibility, NO vmcnt drain (fire-and-forget h stores
// stay off the 2048-iteration critical path)
__device__ __forceinline__ void barrier_lds() {
    asm volatile("s_waitcnt lgkmcnt(0)" ::: "memory");
    __builtin_amdgcn_s_barrier();
    asm volatile("" ::: "memory");
}

template <bool DEFER_FC>
__global__ __launch_bounds__(512) __attribute__((amdgpu_waves_per_eu(2, 2)))
void lstm_k1(const float* __restrict__ x, const float* __restrict__ W_ih,
             const float* __restrict__ W_hh, const float* __restrict__ b_ih,
             const float* __restrict__ b_hh, const float* __restrict__ fc_w,
             const float* __restrict__ fc_b, float* __restrict__ out,
             _Float16* __restrict__ hws) {
    __shared__ __align__(16) float    x_lds[NT];
    __shared__ __align__(16) _Float16 h_lds[2][NH];  // double buffer
    __shared__ float red[8];                         // fallback fc partials

    const int b    = blockIdx.x;
    const int t    = threadIdx.x;   // 0..511
    const int kq   = t & 3;         // K-quarter (lane quad)
    const int unit = t >> 2;        // hidden unit 0..127

    // preload x row (512 x float4)
    ((float4*)x_lds)[t] = ((const float4*)(x + (size_t)b * NT))[t];
    if (t < NH) h_lds[0][t] = (_Float16)0.f;

    // weights: 4 gate rows of `unit`, K-slice [kq*32, kq*32+32) -> 4x16 half2
    unsigned wq[64];
    {
#pragma unroll
        for (int r = 0; r < 4; ++r) {
            const float2* p =
                (const float2*)(W_hh + (size_t)(r * NH + unit) * NH + kq * 32);
#pragma unroll
            for (int k = 0; k < 16; ++k) {
                float2 f = p[k];
                wq[r * 16 + k] = packh2(f.x, f.y);
            }
        }
    }
#pragma unroll
    for (int k = 0; k < 64; ++k) asm volatile("" : "+v"(wq[k]));

    // biases / x-weights (added once, post-combine, on all quad lanes)
    const float bi = b_ih[unit] + b_hh[unit];
    const float bf = b_ih[NH + unit] + b_hh[NH + unit];
    const float bz = b_ih[2 * NH + unit] + b_hh[2 * NH + unit];
    const float bo = b_ih[3 * NH + unit] + b_hh[3 * NH + unit];
    const float wi = W_ih[unit];
    const float wf = W_ih[NH + unit];
    const float wz = W_ih[2 * NH + unit];
    const float wo = W_ih[3 * NH + unit];

    float fcw = 0.f, fcb = 0.f;
    if (!DEFER_FC) {
        fcw = fc_w[unit];
        fcb = fc_b[0];
    }

    float c = 0.f, h = 0.f;  // replicated across the 4 quad lanes
    float*    outp = out + (size_t)b * NT;
    _Float16* hrow = DEFER_FC ? (hws + (size_t)b * NT * NH) : (_Float16*)nullptr;

    __syncthreads();

    for (int step = 0; step < NT; ++step) {
        const uint4* h4 = (const uint4*)h_lds[step & 1];
        float xv = x_lds[step];
        float si0 = 0.f, si1 = 0.f, sf0 = 0.f, sf1 = 0.f;
        float sz0 = 0.f, sz1 = 0.f, so0 = 0.f, so1 = 0.f;
#pragma unroll
        for (int j = 0; j < 4; ++j) {
            uint4 hv = h4[(kq << 2) + j];
            si0 = dot2(wq[4 * j + 0], hv.x, si0);
            si1 = dot2(wq[4 * j + 1], hv.y, si1);
            si0 = dot2(wq[4 * j + 2], hv.z, si0);
            si1 = dot2(wq[4 * j + 3], hv.w, si1);
            sf0 = dot2(wq[16 + 4 * j + 0], hv.x, sf0);
            sf1 = dot2(wq[16 + 4 * j + 1], hv.y, sf1);
            sf0 = dot2(wq[16 + 4 * j + 2], hv.z, sf0);
            sf1 = dot2(wq[16 + 4 * j + 3], hv.w, sf1);
            sz0 = dot2(wq[32 + 4 * j + 0], hv.x, sz0);
            sz1 = dot2(wq[32 + 4 * j + 1], hv.y, sz1);
            sz0 = dot2(wq[32 + 4 * j + 2], hv.z, sz0);
            sz1 = dot2(wq[32 + 4 * j + 3], hv.w, sz1);
            so0 = dot2(wq[48 + 4 * j + 0], hv.x, so0);
            so1 = dot2(wq[48 + 4 * j + 1], hv.y, so1);
            so0 = dot2(wq[48 + 4 * j + 2], hv.z, so0);
            so1 = dot2(wq[48 + 4 * j + 3], hv.w, so1);
        }
        float si = si0 + si1, sf = sf0 + sf1, sz = sz0 + sz1, so = so0 + so1;
        // quad butterfly: all 4 lanes end with the full K=128 sums
        si += __shfl_xor(si, 1);
        sf += __shfl_xor(sf, 1);
        sz += __shfl_xor(sz, 1);
        so += __shfl_xor(so, 1);
        si += __shfl_xor(si, 2);
        sf += __shfl_xor(sf, 2);
        sz += __shfl_xor(sz, 2);
        so += __shfl_xor(so, 2);
        si = fmaf(xv, wi, si + bi);
        sf = fmaf(xv, wf, sf + bf);
        sz = fmaf(xv, wz, sz + bz);
        so = fmaf(xv, wo, so + bo);
        // cell update, redundantly on all 4 quad lanes (identical results)
        float gi = fsig(si), gf = fsig(sf), gz = ftanh(sz), go = fsig(so);
        c = fmaf(gf, c, gi * gz);
        h = go * ftanh(c);
        if (kq == 0) {
            h_lds[(step + 1) & 1][unit] = (_Float16)h;
            if (DEFER_FC) hrow[(size_t)step * NH + unit] = (_Float16)h;
        }
        if (!DEFER_FC) {
            float p = (kq == 0) ? h * fcw : 0.f;
#pragma unroll
            for (int m = 32; m >= 1; m >>= 1) p += __shfl_xor(p, m, 64);
            if ((t & 63) == 0) red[t >> 6] = p;
            __syncthreads();
            if (t == 0) {
                float s = red[0] + red[1] + red[2] + red[3] + red[4] + red[5] +
                          red[6] + red[7];
                outp[step] = ftanh(s + fcb);
            }
        }
        barrier_lds();
    }

    // final hT, cT ([1,B,H] each, after out)
    if (kq == 0) {
        float* hT = out + (size_t)NB * NT;
        float* cT = hT + (size_t)NB * NH;
        hT[b * NH + unit] = h;
        cT[b * NH + unit] = c;
    }
}

// Kernel 2: out[b,t] = tanh(dot(h[b,t,:], fc_w) + fc_b). Memory-bound.
__global__ __launch_bounds__(256) void fc_k2(const _Float16* __restrict__ hws,
                                             const float* __restrict__ fc_w,
                                             const float* __restrict__ fc_b,
                                             float* __restrict__ out) {
    __shared__ unsigned wlds[64];
    const int t = threadIdx.x;
    if (t < 64) {
        float2 f = ((const float2*)fc_w)[t];
        wlds[t] = packh2(f.x, f.y);
    }
    __syncthreads();

    const size_t idx = (size_t)blockIdx.x * 256 + t;
    const uint4* hp = (const uint4*)(hws + idx * NH);
    const uint4* wp = (const uint4*)wlds;
    float acc = 0.f;
#pragma unroll
    for (int j = 0; j < 16; ++j) {
        uint4 hv = hp[j];
        uint4 wv = wp[j];
        acc = dot2(hv.x, wv.x, acc);
        acc = dot2(hv.y, wv.y, acc);
        acc = dot2(hv.z, wv.z, acc);
        acc = dot2(hv.w, wv.w, acc);
    }
    out[idx] = ftanh(acc + fc_b[0]);
}

extern "C" void kernel_launch(void* const* d_in, const int* in_sizes, int n_in,
                              void* d_out, int out_size, void* d_ws, size_t ws_size,
                              hipStream_t stream) {
    const float* x    = (const float*)d_in[0];
    const float* W_ih = (const float*)d_in[1];
    const float* W_hh = (const float*)d_in[2];
    const float* b_ih = (const float*)d_in[3];
    const float* b_hh = (const float*)d_in[4];
    const float* fc_w = (const float*)d_in[5];
    const float* fc_b = (const float*)d_in[6];
    float* out = (float*)d_out;

    const size_t need = (size_t)NB * NT * NH * sizeof(_Float16);  // 128 MB
    if (ws_size >= need) {
        _Float16* hws = (_Float16*)d_ws;
        lstm_k1<true><<<dim3(NB), dim3(512), 0, stream>>>(
            x, W_ih, W_hh, b_ih, b_hh, fc_w, fc_b, out, hws);
        fc_k2<<<dim3(NB * NT / 256), dim3(256), 0, stream>>>(hws, fc_w, fc_b, out);
    } else {
        lstm_k1<false><<<dim3(NB), dim3(512), 0, stream>>>(
            x, W_ih, W_hh, b_ih, b_hh, fc_w, fc_b, out, nullptr);
    }
}

// Round 6
// 1298.406 us; speedup vs baseline: 1.1438x; 1.0161x over previous
//
#include <hip/hip_runtime.h>

// LSTM B=256, T=2048, H=128. One batch row per WG, 512 threads = 128 units
// x 4 K-quarters. Thread (unit,kq) holds the kq*32..kq*32+32 slice of ALL
// FOUR gate rows (i,f,z,o) of its unit: 64 packed half2, asm-pinned.
//
// Round-5 lesson (per-CU LDS-pipe accounting, ~12 cyc/wave-instr):
//   __shfl_xor lowers to ds_bpermute = LDS pipe. 64 bpermutes + 32 h-reads
//   per CU per step ~= 1150 cyc — the real limiter across R1/R3/R5.
// This round: quad butterfly via DPP quad_perm (VALU pipe, v_add+update_dpp,
// ctrl 0xB1 / 0x4E) -> LDS instrs per CU per step drop 112 -> ~48.
//
// Per step (ONE lgkmcnt-only barrier): 4x ds_read_b128 (h slice) -> 64 dot2
// -> 8 DPP adds (all 4 quad lanes get all 4 full gate sums) -> bias/x ->
// activations + cell update redundantly on quad lanes -> kq==0 writes h to
// double-buffered h_lds + fire-and-forget global h store. fc deferred to k2.

typedef _Float16 half2v __attribute__((ext_vector_type(2)));

constexpr int NB = 256;
constexpr int NT = 2048;
constexpr int NH = 128;

__device__ __forceinline__ float fexp2(float x) {
    float r;
    asm("v_exp_f32 %0, %1" : "=v"(r) : "v"(x));
    return r;
}
__device__ __forceinline__ float frcp(float x) {
    float r;
    asm("v_rcp_f32 %0, %1" : "=v"(r) : "v"(x));
    return r;
}
__device__ __forceinline__ float fsig(float x) {   // 1/(1+2^(-x*log2e))
    return frcp(1.f + fexp2(x * -1.44269504f));
}
__device__ __forceinline__ float ftanh(float x) {  // 2/(1+2^(-2x*log2e)) - 1
    return fmaf(2.f, frcp(1.f + fexp2(x * -2.88539008f)), -1.f);
}

__device__ __forceinline__ float dot2(unsigned int w, unsigned int h, float acc) {
    half2v a = __builtin_bit_cast(half2v, w);
    half2v b = __builtin_bit_cast(half2v, h);
#if __has_builtin(__builtin_amdgcn_fdot2)
    return __builtin_amdgcn_fdot2(a, b, acc, false);
#else
    float r;
    asm("v_dot2_f32_f16 %0, %1, %2, %3" : "=v"(r) : "v"(a), "v"(b), "v"(acc));
    return r;
#endif
}

// v += (v from quad_perm<CTRL> lane) — pure VALU (DPP), no LDS pipe.
// 0xB1 = [1,0,3,2] (xor 1), 0x4E = [2,3,0,1] (xor 2).
template <int CTRL>
__device__ __forceinline__ float dpp_add(float v) {
    int s = __builtin_bit_cast(int, v);
    int p = __builtin_amdgcn_update_dpp(s, s, CTRL, 0xF, 0xF, false);
    return v + __builtin_bit_cast(float, p);
}

__device__ __forceinline__ unsigned packh2(float lo, float hi) {
    half2v p;
    p.x = (_Float16)lo;
    p.y = (_Float16)hi;
    return __builtin_bit_cast(unsigned, p);
}

// barrier with LDS visibility, NO vmcnt drain (fire-and-forget h stores
// stay off the 2048-iteration critical path)
__device__ __forceinline__ void barrier_lds() {
    asm volatile("s_waitcnt lgkmcnt(0)" ::: "memory");
    __builtin_amdgcn_s_barrier();
    asm volatile("" ::: "memory");
}

template <bool DEFER_FC>
__global__ __launch_bounds__(512) __attribute__((amdgpu_waves_per_eu(2, 2)))
void lstm_k1(const float* __restrict__ x, const float* __restrict__ W_ih,
             const float* __restrict__ W_hh, const float* __restrict__ b_ih,
             const float* __restrict__ b_hh, const float* __restrict__ fc_w,
             const float* __restrict__ fc_b, float* __restrict__ out,
             _Float16* __restrict__ hws) {
    __shared__ __align__(16) float    x_lds[NT];
    __shared__ __align__(16) _Float16 h_lds[2][NH];  // double buffer
    __shared__ float red[8];                         // fallback fc partials

    const int b    = blockIdx.x;
    const int t    = threadIdx.x;   // 0..511
    const int kq   = t & 3;         // K-quarter (lane quad)
    const int unit = t >> 2;        // hidden unit 0..127

    // preload x row (512 x float4)
    ((float4*)x_lds)[t] = ((const float4*)(x + (size_t)b * NT))[t];
    if (t < NH) h_lds[0][t] = (_Float16)0.f;

    // weights: 4 gate rows of `unit`, K-slice [kq*32, kq*32+32) -> 4x16 half2
    unsigned wq[64];
    {
#pragma unroll
        for (int r = 0; r < 4; ++r) {
            const float2* p =
                (const float2*)(W_hh + (size_t)(r * NH + unit) * NH + kq * 32);
#pragma unroll
            for (int k = 0; k < 16; ++k) {
                float2 f = p[k];
                wq[r * 16 + k] = packh2(f.x, f.y);
            }
        }
    }
#pragma unroll
    for (int k = 0; k < 64; ++k) asm volatile("" : "+v"(wq[k]));

    // biases / x-weights (added once, post-combine, on all quad lanes)
    const float bi = b_ih[unit] + b_hh[unit];
    const float bf = b_ih[NH + unit] + b_hh[NH + unit];
    const float bz = b_ih[2 * NH + unit] + b_hh[2 * NH + unit];
    const float bo = b_ih[3 * NH + unit] + b_hh[3 * NH + unit];
    const float wi = W_ih[unit];
    const float wf = W_ih[NH + unit];
    const float wz = W_ih[2 * NH + unit];
    const float wo = W_ih[3 * NH + unit];

    float fcw = 0.f, fcb = 0.f;
    if (!DEFER_FC) {
        fcw = fc_w[unit];
        fcb = fc_b[0];
    }

    float c = 0.f, h = 0.f;  // replicated across the 4 quad lanes
    float*    outp = out + (size_t)b * NT;
    _Float16* hrow = DEFER_FC ? (hws + (size_t)b * NT * NH) : (_Float16*)nullptr;

    __syncthreads();

    for (int step = 0; step < NT; ++step) {
        const uint4* h4 = (const uint4*)h_lds[step & 1];
        float xv = x_lds[step];
        float si0 = 0.f, si1 = 0.f, sf0 = 0.f, sf1 = 0.f;
        float sz0 = 0.f, sz1 = 0.f, so0 = 0.f, so1 = 0.f;
#pragma unroll
        for (int j = 0; j < 4; ++j) {
            uint4 hv = h4[(kq << 2) + j];
            si0 = dot2(wq[4 * j + 0], hv.x, si0);
            si1 = dot2(wq[4 * j + 1], hv.y, si1);
            si0 = dot2(wq[4 * j + 2], hv.z, si0);
            si1 = dot2(wq[4 * j + 3], hv.w, si1);
            sf0 = dot2(wq[16 + 4 * j + 0], hv.x, sf0);
            sf1 = dot2(wq[16 + 4 * j + 1], hv.y, sf1);
            sf0 = dot2(wq[16 + 4 * j + 2], hv.z, sf0);
            sf1 = dot2(wq[16 + 4 * j + 3], hv.w, sf1);
            sz0 = dot2(wq[32 + 4 * j + 0], hv.x, sz0);
            sz1 = dot2(wq[32 + 4 * j + 1], hv.y, sz1);
            sz0 = dot2(wq[32 + 4 * j + 2], hv.z, sz0);
            sz1 = dot2(wq[32 + 4 * j + 3], hv.w, sz1);
            so0 = dot2(wq[48 + 4 * j + 0], hv.x, so0);
            so1 = dot2(wq[48 + 4 * j + 1], hv.y, so1);
            so0 = dot2(wq[48 + 4 * j + 2], hv.z, so0);
            so1 = dot2(wq[48 + 4 * j + 3], hv.w, so1);
        }
        float si = si0 + si1, sf = sf0 + sf1, sz = sz0 + sz1, so = so0 + so1;
        // quad butterfly on the VALU pipe (DPP quad_perm), not ds_bpermute
        si = dpp_add<0xB1>(si);
        sf = dpp_add<0xB1>(sf);
        sz = dpp_add<0xB1>(sz);
        so = dpp_add<0xB1>(so);
        si = dpp_add<0x4E>(si);
        sf = dpp_add<0x4E>(sf);
        sz = dpp_add<0x4E>(sz);
        so = dpp_add<0x4E>(so);
        si = fmaf(xv, wi, si + bi);
        sf = fmaf(xv, wf, sf + bf);
        sz = fmaf(xv, wz, sz + bz);
        so = fmaf(xv, wo, so + bo);
        // cell update, redundantly on all 4 quad lanes (identical results)
        float gi = fsig(si), gf = fsig(sf), gz = ftanh(sz), go = fsig(so);
        c = fmaf(gf, c, gi * gz);
        h = go * ftanh(c);
        if (kq == 0) {
            h_lds[(step + 1) & 1][unit] = (_Float16)h;
            if (DEFER_FC) hrow[(size_t)step * NH + unit] = (_Float16)h;
        }
        if (!DEFER_FC) {
            float p = (kq == 0) ? h * fcw : 0.f;
#pragma unroll
            for (int m = 32; m >= 1; m >>= 1) p += __shfl_xor(p, m, 64);
            if ((t & 63) == 0) red[t >> 6] = p;
            __syncthreads();
            if (t == 0) {
                float s = red[0] + red[1] + red[2] + red[3] + red[4] + red[5] +
                          red[6] + red[7];
                outp[step] = ftanh(s + fcb);
            }
        }
        barrier_lds();
    }

    // final hT, cT ([1,B,H] each, after out)
    if (kq == 0) {
        float* hT = out + (size_t)NB * NT;
        float* cT = hT + (size_t)NB * NH;
        hT[b * NH + unit] = h;
        cT[b * NH + unit] = c;
    }
}

// Kernel 2: out[b,t] = tanh(dot(h[b,t,:], fc_w) + fc_b). Memory-bound.
__global__ __launch_bounds__(256) void fc_k2(const _Float16* __restrict__ hws,
                                             const float* __restrict__ fc_w,
                                             const float* __restrict__ fc_b,
                                             float* __restrict__ out) {
    __shared__ unsigned wlds[64];
    const int t = threadIdx.x;
    if (t < 64) {
        float2 f = ((const float2*)fc_w)[t];
        wlds[t] = packh2(f.x, f.y);
    }
    __syncthreads();

    const size_t idx = (size_t)blockIdx.x * 256 + t;
    const uint4* hp = (const uint4*)(hws + idx * NH);
    const uint4* wp = (const uint4*)wlds;
    float acc = 0.f;
#pragma unroll
    for (int j = 0; j < 16; ++j) {
        uint4 hv = hp[j];
        uint4 wv = wp[j];
        acc = dot2(hv.x, wv.x, acc);
        acc = dot2(hv.y, wv.y, acc);
        acc = dot2(hv.z, wv.z, acc);
        acc = dot2(hv.w, wv.w, acc);
    }
    out[idx] = ftanh(acc + fc_b[0]);
}

extern "C" void kernel_launch(void* const* d_in, const int* in_sizes, int n_in,
                              void* d_out, int out_size, void* d_ws, size_t ws_size,
                              hipStream_t stream) {
    const float* x    = (const float*)d_in[0];
    const float* W_ih = (const float*)d_in[1];
    const float* W_hh = (const float*)d_in[2];
    const float* b_ih = (const float*)d_in[3];
    const float* b_hh = (const float*)d_in[4];
    const float* fc_w = (const float*)d_in[5];
    const float* fc_b = (const float*)d_in[6];
    float* out = (float*)d_out;

    const size_t need = (size_t)NB * NT * NH * sizeof(_Float16);  // 128 MB
    if (ws_size >= need) {
        _Float16* hws = (_Float16*)d_ws;
        lstm_k1<true><<<dim3(NB), dim3(512), 0, stream>>>(
            x, W_ih, W_hh, b_ih, b_hh, fc_w, fc_b, out, hws);
        fc_k2<<<dim3(NB * NT / 256), dim3(256), 0, stream>>>(hws, fc_w, fc_b, out);
    } else {
        lstm_k1<false><<<dim3(NB), dim3(512), 0, stream>>>(
            x, W_ih, W_hh, b_ih, b_hh, fc_w, fc_b, out, nullptr);
    }
}